// Round 20
// baseline (323.561 us; speedup 1.0000x reference)
//
#include <hip/hip_runtime.h>
#include <math.h>

#define T_DIM 300
#define J_DIM 25
#define CIN 64
#define COUT 128
#define B_DIM 64

typedef __attribute__((ext_vector_type(8))) short bf16x8;
typedef __attribute__((ext_vector_type(4))) float f32x4;

__device__ __forceinline__ unsigned short f2bf(float f) {
    union { float f; unsigned u; } v; v.f = f;
    unsigned r = v.u + 0x7FFF + ((v.u >> 16) & 1);   // RNE
    return (unsigned short)(r >> 16);
}

__device__ __forceinline__ unsigned pkbf(float lo, float hi) {
    return (unsigned)f2bf(lo) | ((unsigned)f2bf(hi) << 16);
}

// ================= scores kernel (R19 text — best measured) =================
#define SC_NSEG 10
#define SC_NCH  3

__global__ __launch_bounds__(256, 2) void scores_kernel(
    const float* __restrict__ x,
    const uint4* __restrict__ Wf,              // prepacked bf16 A-fragments [24][64]
    const float* __restrict__ ba, const float* __restrict__ bb,
    float* __restrict__ part,
    uint4* __restrict__ xpk)                   // out: packed bf16 cells [b][cg][p]
{
    __shared__ uint4 xsf[8][256];              // x B-fragments: [cgrp][pos], 8 ch packed bf16
    __shared__ unsigned short aT1[32][328];    // a1 transposed: [j][t*32 + k]
    __shared__ unsigned short aT2[32][328];

    const int tid  = threadIdx.x;
    const int seg  = blockIdx.x;
    const int b    = blockIdx.y;
    const int lane = tid & 63;
    const int w    = tid >> 6;          // 0..3
    const int g4   = lane >> 4;
    const int c16  = lane & 15;
    const int jt1  = w >> 1, jt2 = w & 1;

    const float* xb = x + (size_t)b * (CIN * T_DIM * J_DIM);
    uint4* xpko = xpk + (size_t)b * 8 * 7500;

    f32x4 gacc[3];
    #pragma unroll
    for (int i = 0; i < 3; ++i) gacc[i] = (f32x4){0.f, 0.f, 0.f, 0.f};

    for (int ch = 0; ch < SC_NCH; ++ch) {
        const int pb = seg * 750 + ch * 250;

        #pragma unroll
        for (int cg = 0; cg < 8; ++cg) {
            int p = pb + tid; if (p > 7499) p = 7499;
            const float* xc = xb + (size_t)(cg * 8) * 7500 + p;
            unsigned d[4];
            #pragma unroll
            for (int m = 0; m < 4; ++m)
                d[m] = (unsigned)f2bf(xc[(2 * m) * 7500]) |
                       ((unsigned)f2bf(xc[(2 * m + 1) * 7500]) << 16);
            uint4 cell = make_uint4(d[0], d[1], d[2], d[3]);
            xsf[cg][tid] = cell;
            xpko[cg * 7500 + p] = cell;        // by-product: packed x for main (dups identical)
        }
        __syncthreads();

        #pragma unroll
        for (int i = 0; i < 3; ++i) {
            #pragma unroll
            for (int pass = 0; pass < 2; ++pass) {
                const float* bs = pass ? bb : ba;
                bf16x8 afr[2][2];
                #pragma unroll
                for (int m = 0; m < 2; ++m)
                    #pragma unroll
                    for (int s = 0; s < 2; ++s)
                        afr[m][s] = *reinterpret_cast<const bf16x8*>(
                            &Wf[((((i * 2 + pass) * 2 + m) * 2 + s) << 6) + lane]);
                f32x4 acc[2][4];
                #pragma unroll
                for (int m = 0; m < 2; ++m) {
                    float4 bv = *(const float4*)(bs + i * 32 + m * 16 + g4 * 4);
                    #pragma unroll
                    for (int n = 0; n < 4; ++n)
                        acc[m][n] = (f32x4){bv.x, bv.y, bv.z, bv.w};
                }
                #pragma unroll
                for (int n = 0; n < 4; ++n) {
                    const int ptile = w * 4 + n;
                    #pragma unroll
                    for (int s = 0; s < 2; ++s) {
                        bf16x8 bfr = *reinterpret_cast<const bf16x8*>(&xsf[s * 4 + g4][ptile * 16 + c16]);
                        #pragma unroll
                        for (int m = 0; m < 2; ++m)
                            acc[m][n] = __builtin_amdgcn_mfma_f32_16x16x32_bf16(
                                afr[m][s], bfr, acc[m][n], 0, 0, 0);
                    }
                }
                unsigned short (*aT)[328] = pass ? aT2 : aT1;
                #pragma unroll
                for (int n = 0; n < 4; ++n) {
                    const int pos = (w * 4 + n) * 16 + c16;
                    if (pos < 250) {
                        const int t = pos / 25, j = pos - t * 25;
                        #pragma unroll
                        for (int m = 0; m < 2; ++m) {
                            const int kbase = t * 32 + m * 16 + g4 * 4;   // consecutive k
                            uint2 pk = make_uint2(pkbf(acc[m][n][0], acc[m][n][1]),
                                                  pkbf(acc[m][n][2], acc[m][n][3]));
                            *reinterpret_cast<uint2*>(&aT[j][kbase]) = pk;
                        }
                    }
                }
            }
            __syncthreads();

            #pragma unroll
            for (int s = 0; s < 10; ++s) {
                bf16x8 af = *reinterpret_cast<const bf16x8*>(&aT1[jt1 * 16 + c16][s * 32 + g4 * 8]);
                bf16x8 bf = *reinterpret_cast<const bf16x8*>(&aT2[jt2 * 16 + c16][s * 32 + g4 * 8]);
                gacc[i] = __builtin_amdgcn_mfma_f32_16x16x32_bf16(af, bf, gacc[i], 0, 0, 0);
            }
            __syncthreads();
        }
    }

    #pragma unroll
    for (int i = 0; i < 3; ++i) {
        const int j2 = jt2 * 16 + c16;
        #pragma unroll
        for (int r = 0; r < 4; ++r) {
            const int j1 = jt1 * 16 + g4 * 4 + r;
            if (j1 < 25 && j2 < 25)
                part[((size_t)(b * 3 + i) * SC_NSEG + seg) * 625 + j1 * 25 + j2] = gacc[i][r];
        }
    }
}

// ================= softmax (R19 text) =================
__global__ void softmax_kernel(const float* __restrict__ part,
                               const float* __restrict__ PA,
                               uint4* __restrict__ Gbg)
{
    int bi = blockIdx.x;
    int b = bi / 3, i = bi - b * 3;
    int j2 = threadIdx.x;
    if (j2 >= 32) return;
    float gval[25];
    if (j2 < 25) {
        float v[25];
        float m = -1e30f;
        #pragma unroll
        for (int j1 = 0; j1 < 25; ++j1) {
            float s = 0.0f;
            for (int seg = 0; seg < SC_NSEG; ++seg)
                s += part[((size_t)bi * SC_NSEG + seg) * 625 + j1 * 25 + j2];
            v[j1] = s * (1.0f / 9600.0f);
            m = fmaxf(m, v[j1]);
        }
        float sum = 0.0f;
        #pragma unroll
        for (int j1 = 0; j1 < 25; ++j1) { v[j1] = expf(v[j1] - m); sum += v[j1]; }
        float r = 1.0f / sum;
        #pragma unroll
        for (int j1 = 0; j1 < 25; ++j1)
            gval[j1] = v[j1] * r + PA[(i * 25 + j1) * 25 + j2] + (j1 == j2 ? 1.0f : 0.0f);
    }
    #pragma unroll
    for (int kg = 0; kg < 4; ++kg) {
        unsigned d[4];
        #pragma unroll
        for (int mm = 0; mm < 4; ++mm) {
            int ja = kg * 8 + 2 * mm, jb2 = ja + 1;
            float va = (j2 < 25 && ja < 25) ? gval[ja] : 0.0f;
            float vb = (j2 < 25 && jb2 < 25) ? gval[jb2] : 0.0f;
            d[mm] = pkbf(va, vb);
        }
        Gbg[((size_t)bi * 4 + kg) * 33 + j2] = make_uint4(d[0], d[1], d[2], d[3]);
    }
}

// ================= prep (R19 text: K-order [Wd0|Wdown|Wd1|Wd2]) =================
__global__ void prep_kernel(
    const float* __restrict__ Wd, const float* __restrict__ bd,
    const float* __restrict__ Wdown, const float* __restrict__ bdown,
    const float* __restrict__ g1, const float* __restrict__ b1,
    const float* __restrict__ m1, const float* __restrict__ v1,
    const float* __restrict__ g2, const float* __restrict__ b2,
    const float* __restrict__ m2, const float* __restrict__ v2,
    const float* __restrict__ Wa, const float* __restrict__ Wb,
    unsigned short* __restrict__ Wpb, float* __restrict__ cst,
    uint4* __restrict__ Wf)
{
    const int tid = threadIdx.x;
    for (int idx = tid; idx < COUT * 256; idx += 256) {
        int o = idx >> 8, k = idx & 255;
        int region = k >> 6;           // 0:Wd0 1:Wdown 2:Wd1 3:Wd2
        float val;
        if (region == 1) {
            float inv = g2[o] * rsqrtf(v2[o] + 1e-5f);
            val = Wdown[o * 64 + (k & 63)] * inv;
        } else {
            int i = (region == 0) ? 0 : region - 1;
            float inv = g1[o] * rsqrtf(v1[o] + 1e-5f);
            val = Wd[(i * COUT + o) * 64 + (k & 63)] * inv;
        }
        Wpb[idx] = f2bf(val);
    }
    for (int idx = tid; idx < 24 * 64; idx += 256) {
        const int fi = idx >> 6, lane = idx & 63;
        const int i = fi >> 3, pass = (fi >> 2) & 1, m = (fi >> 1) & 1, s = fi & 1;
        const int g4 = lane >> 4, c16 = lane & 15;
        const float* W = pass ? Wb : Wa;
        const float* wp = W + i * 2048 + (m * 16 + c16) * 64 + s * 32 + g4 * 8;
        Wf[idx] = make_uint4(pkbf(wp[0], wp[1]), pkbf(wp[2], wp[3]),
                             pkbf(wp[4], wp[5]), pkbf(wp[6], wp[7]));
    }
    if (tid < COUT) {
        int o = tid;
        float inv1 = g1[o] * rsqrtf(v1[o] + 1e-5f);
        float inv2 = g2[o] * rsqrtf(v2[o] + 1e-5f);
        cst[o] = (bd[o] + bd[COUT + o] + bd[2 * COUT + o]) * inv1
               + (b1[o] - m1[o] * inv1)
               + bdown[o] * inv2
               + (b2[o] - m2[o] * inv2);
    }
}

// ================= main fused kernel: persistent blocks, 5 chunks each (R19 phases) =================
#define M_CPB 5      // chunks (of 4 t) per block

__global__ __launch_bounds__(512, 8) void main_kernel(
    const uint4* __restrict__ xpk, const uint4* __restrict__ Gbg,
    const unsigned short* __restrict__ Wpb, const float* __restrict__ cst,
    float* __restrict__ out)
{
    __shared__ uint4 zxs[16][113];             // half-K B tile: [kgrp(8k)][pos]
    __shared__ uint4 gb[396];                  // [(i*4+kg)*33 + col]

    const int tid  = threadIdx.x;
    const int b    = blockIdx.y;
    const int lane = tid & 63;
    const int w    = __builtin_amdgcn_readfirstlane(tid >> 6);  // wave 0..7
    const int g4   = lane >> 4;       // 0..3
    const int c16  = lane & 15;       // 0..15

    const int zt = w >> 1;            // wave's t row (0..3)
    const int mh = w & 1;             // wave's c-half

    // gb loaded once per block (visible after first in-loop barrier)
    if (tid < 396) gb[tid] = Gbg[(size_t)b * 396 + tid];

    for (int it = 0; it < M_CPB; ++it) {
        const int t0 = (blockIdx.x * M_CPB + it) * 4;

        // ---- stage: x copy into zxs kgrps 8..15 — direct uint4 copy from xpk ----
        {
            const uint4* xpb = xpk + (size_t)b * 8 * 7500 + t0 * 25;
            for (int idx = tid; idx < 800; idx += 512) {
                int kgl = idx / 100, q = idx - kgl * 100;
                zxs[8 + kgl][q] = xpb[kgl * 7500 + q];
            }
        }

        f32x4 acc[7];
        #pragma unroll
        for (int n = 0; n < 7; ++n) acc[n] = (f32x4){0.f, 0.f, 0.f, 0.f};

        __syncthreads();

        // z A-fragments (x_t rows) read from the zxs x-copy (registers carry past overwrite)
        bf16x8 a_x[2];
        #pragma unroll
        for (int m = 0; m < 2; ++m) {
            const int cA = (mh * 2 + m) * 16 + c16;
            const unsigned short* src = (const unsigned short*)&zxs[8 + (cA >> 3)][zt * 25] + (cA & 7);
            bf16x8 t;
            #pragma unroll
            for (int e = 0; e < 8; ++e) {
                const int jp = g4 * 8 + e;
                t[e] = (jp < 25) ? (short)src[jp * 8] : (short)0;
            }
            a_x[m] = t;
        }

        // z-pass for subset i -> zxs kgrp base kb
        auto zpass = [&](int i, int kb) {
            #pragma unroll
            for (int n = 0; n < 2; ++n) {
                bf16x8 bfr = *reinterpret_cast<const bf16x8*>(&gb[(i * 4 + g4) * 33 + n * 16 + c16]);
                #pragma unroll
                for (int m = 0; m < 2; ++m) {
                    f32x4 d = __builtin_amdgcn_mfma_f32_16x16x32_bf16(
                        a_x[m], bfr, (f32x4){0.f, 0.f, 0.f, 0.f}, 0, 0, 0);
                    const int j = n * 16 + c16;
                    if (j < 25) {
                        const int cb = (mh * 2 + m) * 16 + g4 * 4;   // lane's 4 c-rows start
                        const int kg = kb + (cb >> 3);
                        const int hf = (cb >> 2) & 1;
                        unsigned lo = pkbf(d[0], d[1]), hi = pkbf(d[2], d[3]);
                        *reinterpret_cast<uint2*>(
                            reinterpret_cast<char*>(&zxs[kg][zt * 25 + j]) + hf * 8) = make_uint2(lo, hi);
                    }
                }
            }
        };

        zpass(0, 0);                       // z0 -> kgrps 0..7 (x already in 8..15)
        __syncthreads();

        // ---- GEMM h0 (k 0..127 = [Wd0 | Wdown]) ----
        {
            const unsigned short* wrow = Wpb + (w * 16 + c16) * 256 + g4 * 8;
            #pragma unroll
            for (int kk = 0; kk < 4; ++kk) {
                bf16x8 afr = *reinterpret_cast<const bf16x8*>(wrow + kk * 32);
                #pragma unroll
                for (int n = 0; n < 7; ++n) {
                    bf16x8 bfr = *reinterpret_cast<const bf16x8*>(&zxs[kk * 4 + g4][n * 16 + c16]);
                    acc[n] = __builtin_amdgcn_mfma_f32_16x16x32_bf16(afr, bfr, acc[n], 0, 0, 0);
                }
            }
        }
        __syncthreads();

        zpass(1, 0);                       // z1 -> kgrps 0..7
        zpass(2, 8);                       // z2 -> kgrps 8..15
        __syncthreads();

        // ---- GEMM h1 (k 128..255 = [Wd1 | Wd2]) ----
        {
            const unsigned short* wrow = Wpb + (w * 16 + c16) * 256 + 128 + g4 * 8;
            #pragma unroll
            for (int kk = 0; kk < 4; ++kk) {
                bf16x8 afr = *reinterpret_cast<const bf16x8*>(wrow + kk * 32);
                #pragma unroll
                for (int n = 0; n < 7; ++n) {
                    bf16x8 bfr = *reinterpret_cast<const bf16x8*>(&zxs[kk * 4 + g4][n * 16 + c16]);
                    acc[n] = __builtin_amdgcn_mfma_f32_16x16x32_bf16(afr, bfr, acc[n], 0, 0, 0);
                }
            }
        }

        // ---- epilogue: relu(acc + cst) -> out ----
        float* ob = out + (size_t)b * (COUT * T_DIM * J_DIM) + t0 * 25;
        #pragma unroll
        for (int r = 0; r < 4; ++r) {
            const int o = w * 16 + g4 * 4 + r;
            const float cv = cst[o];
            #pragma unroll
            for (int n = 0; n < 7; ++n) {
                const int pos = n * 16 + c16;
                if (pos < 100)
                    ob[(size_t)o * 7500 + pos] = fmaxf(acc[n][r] + cv, 0.0f);
            }
        }

        if (it != M_CPB - 1) __syncthreads();   // protect zxs before next chunk's staging
    }
}

extern "C" void kernel_launch(void* const* d_in, const int* in_sizes, int n_in,
                              void* d_out, int out_size, void* d_ws, size_t ws_size,
                              hipStream_t stream)
{
    const float* x     = (const float*)d_in[0];
    const float* PA    = (const float*)d_in[1];
    const float* Wa    = (const float*)d_in[2];
    const float* ba    = (const float*)d_in[3];
    const float* Wb    = (const float*)d_in[4];
    const float* bb    = (const float*)d_in[5];
    const float* Wd    = (const float*)d_in[6];
    const float* bd    = (const float*)d_in[7];
    const float* Wdown = (const float*)d_in[8];
    const float* bdown = (const float*)d_in[9];
    const float* bn_g  = (const float*)d_in[10];
    const float* bn_b  = (const float*)d_in[11];
    const float* bn_m  = (const float*)d_in[12];
    const float* bn_v  = (const float*)d_in[13];
    const float* dn_g  = (const float*)d_in[14];
    const float* dn_b  = (const float*)d_in[15];
    const float* dn_m  = (const float*)d_in[16];
    const float* dn_v  = (const float*)d_in[17];

    float* ws   = (float*)d_ws;
    float* part = ws;                                      // 1,200,000 f32
    uint4* Gbg  = (uint4*)(ws + 1200000);                  // 64*396 uint4
    float* cst  = ws + 1301376;                            // 128 f32
    unsigned short* Wpb = (unsigned short*)(ws + 1301504); // 32,768 bf16 (16,384 f32)
    uint4* Wf   = (uint4*)(ws + 1317888);                  // 1536 uint4 (6,144 f32)
    uint4* xpk  = (uint4*)(ws + 1324032);                  // 64*8*7500 uint4 (15,360,000 f32)

    prep_kernel<<<1, 256, 0, stream>>>(Wd, bd, Wdown, bdown,
        bn_g, bn_b, bn_m, bn_v, dn_g, dn_b, dn_m, dn_v, Wa, Wb, Wpb, cst, Wf);
    scores_kernel<<<dim3(SC_NSEG, B_DIM), 256, 0, stream>>>(x, Wf, ba, bb, part, xpk);
    softmax_kernel<<<dim3(B_DIM * 3), 64, 0, stream>>>(part, PA, Gbg);
    main_kernel<<<dim3(T_DIM / 4 / M_CPB, B_DIM), 512, 0, stream>>>(xpk, Gbg, Wpb, cst, (float*)d_out);
}

// Round 21
// 255.066 us; speedup vs baseline: 1.2685x; 1.2685x over previous
//
#include <hip/hip_runtime.h>
#include <math.h>

#define T_DIM 300
#define J_DIM 25
#define CIN 64
#define COUT 128
#define B_DIM 64

typedef __attribute__((ext_vector_type(8))) short bf16x8;
typedef __attribute__((ext_vector_type(4))) float f32x4;

__device__ __forceinline__ unsigned short f2bf(float f) {
    union { float f; unsigned u; } v; v.f = f;
    unsigned r = v.u + 0x7FFF + ((v.u >> 16) & 1);   // RNE
    return (unsigned short)(r >> 16);
}

__device__ __forceinline__ unsigned pkbf(float lo, float hi) {
    return (unsigned)f2bf(lo) | ((unsigned)f2bf(hi) << 16);
}

// ================= scores kernel: persistent stride over 1920 chunk-items (R19 body) =================
#define SC_NSEG 30
#define SC_NITEM (B_DIM * SC_NSEG)   // 1920
#define SC_GRID 512

__global__ __launch_bounds__(256, 2) void scores_kernel(
    const float* __restrict__ x,
    const uint4* __restrict__ Wf,              // prepacked bf16 A-fragments [24][64]
    const float* __restrict__ ba, const float* __restrict__ bb,
    float* __restrict__ part,
    uint4* __restrict__ xpk)                   // out: packed bf16 cells [b][cg][p]
{
    __shared__ uint4 xsf[8][256];              // x B-fragments: [cgrp][pos], 8 ch packed bf16
    __shared__ unsigned short aT1[32][328];    // a1 transposed: [j][t*32 + k]
    __shared__ unsigned short aT2[32][328];

    const int tid  = threadIdx.x;
    const int lane = tid & 63;
    const int w    = tid >> 6;          // 0..3
    const int g4   = lane >> 4;
    const int c16  = lane & 15;
    const int jt1  = w >> 1, jt2 = w & 1;

    for (int q = blockIdx.x; q < SC_NITEM; q += SC_GRID) {
        const int b   = q / SC_NSEG;
        const int seg = q - b * SC_NSEG;
        const int pb  = seg * 250;

        const float* xb = x + (size_t)b * (CIN * T_DIM * J_DIM);
        uint4* xpko = xpk + (size_t)b * 8 * 7500;

        f32x4 gacc[3];
        #pragma unroll
        for (int i = 0; i < 3; ++i) gacc[i] = (f32x4){0.f, 0.f, 0.f, 0.f};

        // ---- stage chunk (250 pos) + xpk writeback ----
        #pragma unroll
        for (int cg = 0; cg < 8; ++cg) {
            int p = pb + tid; if (p > 7499) p = 7499;
            const float* xc = xb + (size_t)(cg * 8) * 7500 + p;
            unsigned d[4];
            #pragma unroll
            for (int m = 0; m < 4; ++m)
                d[m] = (unsigned)f2bf(xc[(2 * m) * 7500]) |
                       ((unsigned)f2bf(xc[(2 * m + 1) * 7500]) << 16);
            uint4 cell = make_uint4(d[0], d[1], d[2], d[3]);
            xsf[cg][tid] = cell;
            xpko[cg * 7500 + p] = cell;        // by-product: packed x for main (dups identical)
        }
        __syncthreads();

        #pragma unroll
        for (int i = 0; i < 3; ++i) {
            #pragma unroll
            for (int pass = 0; pass < 2; ++pass) {
                const float* bs = pass ? bb : ba;
                bf16x8 afr[2][2];
                #pragma unroll
                for (int m = 0; m < 2; ++m)
                    #pragma unroll
                    for (int s = 0; s < 2; ++s)
                        afr[m][s] = *reinterpret_cast<const bf16x8*>(
                            &Wf[((((i * 2 + pass) * 2 + m) * 2 + s) << 6) + lane]);
                f32x4 acc[2][4];
                #pragma unroll
                for (int m = 0; m < 2; ++m) {
                    float4 bv = *(const float4*)(bs + i * 32 + m * 16 + g4 * 4);
                    #pragma unroll
                    for (int n = 0; n < 4; ++n)
                        acc[m][n] = (f32x4){bv.x, bv.y, bv.z, bv.w};
                }
                #pragma unroll
                for (int n = 0; n < 4; ++n) {
                    const int ptile = w * 4 + n;
                    #pragma unroll
                    for (int s = 0; s < 2; ++s) {
                        bf16x8 bfr = *reinterpret_cast<const bf16x8*>(&xsf[s * 4 + g4][ptile * 16 + c16]);
                        #pragma unroll
                        for (int m = 0; m < 2; ++m)
                            acc[m][n] = __builtin_amdgcn_mfma_f32_16x16x32_bf16(
                                afr[m][s], bfr, acc[m][n], 0, 0, 0);
                    }
                }
                unsigned short (*aT)[328] = pass ? aT2 : aT1;
                #pragma unroll
                for (int n = 0; n < 4; ++n) {
                    const int pos = (w * 4 + n) * 16 + c16;
                    if (pos < 250) {
                        const int t = pos / 25, j = pos - t * 25;
                        #pragma unroll
                        for (int m = 0; m < 2; ++m) {
                            const int kbase = t * 32 + m * 16 + g4 * 4;   // consecutive k
                            uint2 pk = make_uint2(pkbf(acc[m][n][0], acc[m][n][1]),
                                                  pkbf(acc[m][n][2], acc[m][n][3]));
                            *reinterpret_cast<uint2*>(&aT[j][kbase]) = pk;
                        }
                    }
                }
            }
            __syncthreads();

            #pragma unroll
            for (int s = 0; s < 10; ++s) {
                bf16x8 af = *reinterpret_cast<const bf16x8*>(&aT1[jt1 * 16 + c16][s * 32 + g4 * 8]);
                bf16x8 bf = *reinterpret_cast<const bf16x8*>(&aT2[jt2 * 16 + c16][s * 32 + g4 * 8]);
                gacc[i] = __builtin_amdgcn_mfma_f32_16x16x32_bf16(af, bf, gacc[i], 0, 0, 0);
            }
            __syncthreads();
        }

        // ---- write this item's partial scores ----
        #pragma unroll
        for (int i = 0; i < 3; ++i) {
            const int j2 = jt2 * 16 + c16;
            #pragma unroll
            for (int r = 0; r < 4; ++r) {
                const int j1 = jt1 * 16 + g4 * 4 + r;
                if (j1 < 25 && j2 < 25)
                    part[((size_t)(b * 3 + i) * SC_NSEG + seg) * 625 + j1 * 25 + j2] = gacc[i][r];
            }
        }
        __syncthreads();   // protect xsf/aT before next item's stage
    }
}

// ================= softmax (R19 text, SC_NSEG macro-driven = 30) =================
__global__ void softmax_kernel(const float* __restrict__ part,
                               const float* __restrict__ PA,
                               uint4* __restrict__ Gbg)
{
    int bi = blockIdx.x;
    int b = bi / 3, i = bi - b * 3;
    int j2 = threadIdx.x;
    if (j2 >= 32) return;
    float gval[25];
    if (j2 < 25) {
        float v[25];
        float m = -1e30f;
        #pragma unroll
        for (int j1 = 0; j1 < 25; ++j1) {
            float s = 0.0f;
            for (int seg = 0; seg < SC_NSEG; ++seg)
                s += part[((size_t)bi * SC_NSEG + seg) * 625 + j1 * 25 + j2];
            v[j1] = s * (1.0f / 9600.0f);
            m = fmaxf(m, v[j1]);
        }
        float sum = 0.0f;
        #pragma unroll
        for (int j1 = 0; j1 < 25; ++j1) { v[j1] = expf(v[j1] - m); sum += v[j1]; }
        float r = 1.0f / sum;
        #pragma unroll
        for (int j1 = 0; j1 < 25; ++j1)
            gval[j1] = v[j1] * r + PA[(i * 25 + j1) * 25 + j2] + (j1 == j2 ? 1.0f : 0.0f);
    }
    #pragma unroll
    for (int kg = 0; kg < 4; ++kg) {
        unsigned d[4];
        #pragma unroll
        for (int mm = 0; mm < 4; ++mm) {
            int ja = kg * 8 + 2 * mm, jb2 = ja + 1;
            float va = (j2 < 25 && ja < 25) ? gval[ja] : 0.0f;
            float vb = (j2 < 25 && jb2 < 25) ? gval[jb2] : 0.0f;
            d[mm] = pkbf(va, vb);
        }
        Gbg[((size_t)bi * 4 + kg) * 33 + j2] = make_uint4(d[0], d[1], d[2], d[3]);
    }
}

// ================= prep (R19 text: K-order [Wd0|Wdown|Wd1|Wd2]) =================
__global__ void prep_kernel(
    const float* __restrict__ Wd, const float* __restrict__ bd,
    const float* __restrict__ Wdown, const float* __restrict__ bdown,
    const float* __restrict__ g1, const float* __restrict__ b1,
    const float* __restrict__ m1, const float* __restrict__ v1,
    const float* __restrict__ g2, const float* __restrict__ b2,
    const float* __restrict__ m2, const float* __restrict__ v2,
    const float* __restrict__ Wa, const float* __restrict__ Wb,
    unsigned short* __restrict__ Wpb, float* __restrict__ cst,
    uint4* __restrict__ Wf)
{
    const int tid = threadIdx.x;
    for (int idx = tid; idx < COUT * 256; idx += 256) {
        int o = idx >> 8, k = idx & 255;
        int region = k >> 6;           // 0:Wd0 1:Wdown 2:Wd1 3:Wd2
        float val;
        if (region == 1) {
            float inv = g2[o] * rsqrtf(v2[o] + 1e-5f);
            val = Wdown[o * 64 + (k & 63)] * inv;
        } else {
            int i = (region == 0) ? 0 : region - 1;
            float inv = g1[o] * rsqrtf(v1[o] + 1e-5f);
            val = Wd[(i * COUT + o) * 64 + (k & 63)] * inv;
        }
        Wpb[idx] = f2bf(val);
    }
    for (int idx = tid; idx < 24 * 64; idx += 256) {
        const int fi = idx >> 6, lane = idx & 63;
        const int i = fi >> 3, pass = (fi >> 2) & 1, m = (fi >> 1) & 1, s = fi & 1;
        const int g4 = lane >> 4, c16 = lane & 15;
        const float* W = pass ? Wb : Wa;
        const float* wp = W + i * 2048 + (m * 16 + c16) * 64 + s * 32 + g4 * 8;
        Wf[idx] = make_uint4(pkbf(wp[0], wp[1]), pkbf(wp[2], wp[3]),
                             pkbf(wp[4], wp[5]), pkbf(wp[6], wp[7]));
    }
    if (tid < COUT) {
        int o = tid;
        float inv1 = g1[o] * rsqrtf(v1[o] + 1e-5f);
        float inv2 = g2[o] * rsqrtf(v2[o] + 1e-5f);
        cst[o] = (bd[o] + bd[COUT + o] + bd[2 * COUT + o]) * inv1
               + (b1[o] - m1[o] * inv1)
               + bdown[o] * inv2
               + (b2[o] - m2[o] * inv2);
    }
}

// ================= main fused kernel (exact R19 text — best measured) =================
#define M_NCH 75     // chunks of 4 t

__global__ __launch_bounds__(512, 8) void main_kernel(
    const uint4* __restrict__ xpk, const uint4* __restrict__ Gbg,
    const unsigned short* __restrict__ Wpb, const float* __restrict__ cst,
    float* __restrict__ out)
{
    __shared__ uint4 zxs[16][113];             // half-K B tile: [kgrp(8k)][pos]
    __shared__ uint4 gb[396];                  // [(i*4+kg)*33 + col]

    const int tid  = threadIdx.x;
    const int b    = blockIdx.y;
    const int t0   = blockIdx.x * 4;
    const int lane = tid & 63;
    const int w    = __builtin_amdgcn_readfirstlane(tid >> 6);  // wave 0..7
    const int g4   = lane >> 4;       // 0..3
    const int c16  = lane & 15;       // 0..15

    // ---- stage: x copy into zxs kgrps 8..15 — direct uint4 copy from xpk ----
    {
        const uint4* xpb = xpk + (size_t)b * 8 * 7500 + t0 * 25;
        for (int idx = tid; idx < 800; idx += 512) {
            int kgl = idx / 100, q = idx - kgl * 100;
            zxs[8 + kgl][q] = xpb[kgl * 7500 + q];
        }
    }
    if (tid < 396) gb[tid] = Gbg[(size_t)b * 396 + tid];

    f32x4 acc[7];
    #pragma unroll
    for (int n = 0; n < 7; ++n) acc[n] = (f32x4){0.f, 0.f, 0.f, 0.f};

    const int zt = w >> 1;            // wave's t row (0..3)
    const int mh = w & 1;             // wave's c-half

    __syncthreads();

    // z A-fragments (x_t rows) read from the zxs x-copy (registers carry them past overwrite)
    bf16x8 a_x[2];
    #pragma unroll
    for (int m = 0; m < 2; ++m) {
        const int cA = (mh * 2 + m) * 16 + c16;
        const unsigned short* src = (const unsigned short*)&zxs[8 + (cA >> 3)][zt * 25] + (cA & 7);
        bf16x8 t;
        #pragma unroll
        for (int e = 0; e < 8; ++e) {
            const int jp = g4 * 8 + e;
            t[e] = (jp < 25) ? (short)src[jp * 8] : (short)0;
        }
        a_x[m] = t;
    }

    // z-pass for subset i -> zxs kgrp base kb
    auto zpass = [&](int i, int kb) {
        #pragma unroll
        for (int n = 0; n < 2; ++n) {
            bf16x8 bfr = *reinterpret_cast<const bf16x8*>(&gb[(i * 4 + g4) * 33 + n * 16 + c16]);
            #pragma unroll
            for (int m = 0; m < 2; ++m) {
                f32x4 d = __builtin_amdgcn_mfma_f32_16x16x32_bf16(
                    a_x[m], bfr, (f32x4){0.f, 0.f, 0.f, 0.f}, 0, 0, 0);
                const int j = n * 16 + c16;
                if (j < 25) {
                    const int cb = (mh * 2 + m) * 16 + g4 * 4;   // lane's 4 c-rows start
                    const int kg = kb + (cb >> 3);
                    const int hf = (cb >> 2) & 1;
                    unsigned lo = pkbf(d[0], d[1]), hi = pkbf(d[2], d[3]);
                    *reinterpret_cast<uint2*>(
                        reinterpret_cast<char*>(&zxs[kg][zt * 25 + j]) + hf * 8) = make_uint2(lo, hi);
                }
            }
        }
    };

    zpass(0, 0);                       // z0 -> kgrps 0..7 (x already in 8..15)
    __syncthreads();

    // ---- GEMM h0 (k 0..127 = [Wd0 | Wdown]) ----
    {
        const unsigned short* wrow = Wpb + (w * 16 + c16) * 256 + g4 * 8;
        #pragma unroll
        for (int kk = 0; kk < 4; ++kk) {
            bf16x8 afr = *reinterpret_cast<const bf16x8*>(wrow + kk * 32);
            #pragma unroll
            for (int n = 0; n < 7; ++n) {
                bf16x8 bfr = *reinterpret_cast<const bf16x8*>(&zxs[kk * 4 + g4][n * 16 + c16]);
                acc[n] = __builtin_amdgcn_mfma_f32_16x16x32_bf16(afr, bfr, acc[n], 0, 0, 0);
            }
        }
    }
    __syncthreads();

    zpass(1, 0);                       // z1 -> kgrps 0..7
    zpass(2, 8);                       // z2 -> kgrps 8..15
    __syncthreads();

    // ---- GEMM h1 (k 128..255 = [Wd1 | Wd2]) ----
    {
        const unsigned short* wrow = Wpb + (w * 16 + c16) * 256 + 128 + g4 * 8;
        #pragma unroll
        for (int kk = 0; kk < 4; ++kk) {
            bf16x8 afr = *reinterpret_cast<const bf16x8*>(wrow + kk * 32);
            #pragma unroll
            for (int n = 0; n < 7; ++n) {
                bf16x8 bfr = *reinterpret_cast<const bf16x8*>(&zxs[kk * 4 + g4][n * 16 + c16]);
                acc[n] = __builtin_amdgcn_mfma_f32_16x16x32_bf16(afr, bfr, acc[n], 0, 0, 0);
            }
        }
    }

    // ---- epilogue: relu(acc + cst) -> out ----
    float* ob = out + (size_t)b * (COUT * T_DIM * J_DIM) + t0 * 25;
    #pragma unroll
    for (int r = 0; r < 4; ++r) {
        const int o = w * 16 + g4 * 4 + r;
        const float cv = cst[o];
        #pragma unroll
        for (int n = 0; n < 7; ++n) {
            const int pos = n * 16 + c16;
            if (pos < 100)
                ob[(size_t)o * 7500 + pos] = fmaxf(acc[n][r] + cv, 0.0f);
        }
    }
}

extern "C" void kernel_launch(void* const* d_in, const int* in_sizes, int n_in,
                              void* d_out, int out_size, void* d_ws, size_t ws_size,
                              hipStream_t stream)
{
    const float* x     = (const float*)d_in[0];
    const float* PA    = (const float*)d_in[1];
    const float* Wa    = (const float*)d_in[2];
    const float* ba    = (const float*)d_in[3];
    const float* Wb    = (const float*)d_in[4];
    const float* bb    = (const float*)d_in[5];
    const float* Wd    = (const float*)d_in[6];
    const float* bd    = (const float*)d_in[7];
    const float* Wdown = (const float*)d_in[8];
    const float* bdown = (const float*)d_in[9];
    const float* bn_g  = (const float*)d_in[10];
    const float* bn_b  = (const float*)d_in[11];
    const float* bn_m  = (const float*)d_in[12];
    const float* bn_v  = (const float*)d_in[13];
    const float* dn_g  = (const float*)d_in[14];
    const float* dn_b  = (const float*)d_in[15];
    const float* dn_m  = (const float*)d_in[16];
    const float* dn_v  = (const float*)d_in[17];

    float* ws   = (float*)d_ws;
    float* part = ws;                                      // 64*3*30*625 = 3,600,000 f32
    uint4* Gbg  = (uint4*)(ws + 3600000);                  // 64*396 uint4 (101,376 f32)
    float* cst  = ws + 3701376;                            // 128 f32
    unsigned short* Wpb = (unsigned short*)(ws + 3701504); // 32,768 bf16 (16,384 f32)
    uint4* Wf   = (uint4*)(ws + 3717888);                  // 1536 uint4 (6,144 f32)
    uint4* xpk  = (uint4*)(ws + 3724032);                  // 64*8*7500 uint4 (15,360,000 f32)

    prep_kernel<<<1, 256, 0, stream>>>(Wd, bd, Wdown, bdown,
        bn_g, bn_b, bn_m, bn_v, dn_g, dn_b, dn_m, dn_v, Wa, Wb, Wpb, cst, Wf);
    scores_kernel<<<dim3(SC_GRID), 256, 0, stream>>>(x, Wf, ba, bb, part, xpk);
    softmax_kernel<<<dim3(B_DIM * 3), 64, 0, stream>>>(part, PA, Gbg);
    main_kernel<<<dim3(M_NCH, B_DIM), 512, 0, stream>>>(xpk, Gbg, Wpb, cst, (float*)d_out);
}

// Round 22
// 229.307 us; speedup vs baseline: 1.4110x; 1.1123x over previous
//
#include <hip/hip_runtime.h>
#include <math.h>

#define T_DIM 300
#define J_DIM 25
#define CIN 64
#define COUT 128
#define B_DIM 64

typedef __attribute__((ext_vector_type(8))) short bf16x8;
typedef __attribute__((ext_vector_type(4))) float f32x4;

__device__ __forceinline__ unsigned short f2bf(float f) {
    union { float f; unsigned u; } v; v.f = f;
    unsigned r = v.u + 0x7FFF + ((v.u >> 16) & 1);   // RNE
    return (unsigned short)(r >> 16);
}

__device__ __forceinline__ unsigned pkbf(float lo, float hi) {
    return (unsigned)f2bf(lo) | ((unsigned)f2bf(hi) << 16);
}

// ================= scores kernel (R19 text — best measured) =================
#define SC_NSEG 10
#define SC_NCH  3

__global__ __launch_bounds__(256, 2) void scores_kernel(
    const float* __restrict__ x,
    const uint4* __restrict__ Wf,              // prepacked bf16 A-fragments [24][64]
    const float* __restrict__ ba, const float* __restrict__ bb,
    float* __restrict__ part,
    uint4* __restrict__ xpk)                   // out: packed bf16 cells [b][cg][p]
{
    __shared__ uint4 xsf[8][256];              // x B-fragments: [cgrp][pos], 8 ch packed bf16
    __shared__ unsigned short aT1[32][328];    // a1 transposed: [j][t*32 + k]
    __shared__ unsigned short aT2[32][328];

    const int tid  = threadIdx.x;
    const int seg  = blockIdx.x;
    const int b    = blockIdx.y;
    const int lane = tid & 63;
    const int w    = tid >> 6;          // 0..3
    const int g4   = lane >> 4;
    const int c16  = lane & 15;
    const int jt1  = w >> 1, jt2 = w & 1;

    const float* xb = x + (size_t)b * (CIN * T_DIM * J_DIM);
    uint4* xpko = xpk + (size_t)b * 8 * 7500;

    f32x4 gacc[3];
    #pragma unroll
    for (int i = 0; i < 3; ++i) gacc[i] = (f32x4){0.f, 0.f, 0.f, 0.f};

    for (int ch = 0; ch < SC_NCH; ++ch) {
        const int pb = seg * 750 + ch * 250;

        #pragma unroll
        for (int cg = 0; cg < 8; ++cg) {
            int p = pb + tid; if (p > 7499) p = 7499;
            const float* xc = xb + (size_t)(cg * 8) * 7500 + p;
            unsigned d[4];
            #pragma unroll
            for (int m = 0; m < 4; ++m)
                d[m] = (unsigned)f2bf(xc[(2 * m) * 7500]) |
                       ((unsigned)f2bf(xc[(2 * m + 1) * 7500]) << 16);
            uint4 cell = make_uint4(d[0], d[1], d[2], d[3]);
            xsf[cg][tid] = cell;
            xpko[cg * 7500 + p] = cell;        // by-product: packed x for main (dups identical)
        }
        __syncthreads();

        #pragma unroll
        for (int i = 0; i < 3; ++i) {
            #pragma unroll
            for (int pass = 0; pass < 2; ++pass) {
                const float* bs = pass ? bb : ba;
                bf16x8 afr[2][2];
                #pragma unroll
                for (int m = 0; m < 2; ++m)
                    #pragma unroll
                    for (int s = 0; s < 2; ++s)
                        afr[m][s] = *reinterpret_cast<const bf16x8*>(
                            &Wf[((((i * 2 + pass) * 2 + m) * 2 + s) << 6) + lane]);
                f32x4 acc[2][4];
                #pragma unroll
                for (int m = 0; m < 2; ++m) {
                    float4 bv = *(const float4*)(bs + i * 32 + m * 16 + g4 * 4);
                    #pragma unroll
                    for (int n = 0; n < 4; ++n)
                        acc[m][n] = (f32x4){bv.x, bv.y, bv.z, bv.w};
                }
                #pragma unroll
                for (int n = 0; n < 4; ++n) {
                    const int ptile = w * 4 + n;
                    #pragma unroll
                    for (int s = 0; s < 2; ++s) {
                        bf16x8 bfr = *reinterpret_cast<const bf16x8*>(&xsf[s * 4 + g4][ptile * 16 + c16]);
                        #pragma unroll
                        for (int m = 0; m < 2; ++m)
                            acc[m][n] = __builtin_amdgcn_mfma_f32_16x16x32_bf16(
                                afr[m][s], bfr, acc[m][n], 0, 0, 0);
                    }
                }
                unsigned short (*aT)[328] = pass ? aT2 : aT1;
                #pragma unroll
                for (int n = 0; n < 4; ++n) {
                    const int pos = (w * 4 + n) * 16 + c16;
                    if (pos < 250) {
                        const int t = pos / 25, j = pos - t * 25;
                        #pragma unroll
                        for (int m = 0; m < 2; ++m) {
                            const int kbase = t * 32 + m * 16 + g4 * 4;   // consecutive k
                            uint2 pk = make_uint2(pkbf(acc[m][n][0], acc[m][n][1]),
                                                  pkbf(acc[m][n][2], acc[m][n][3]));
                            *reinterpret_cast<uint2*>(&aT[j][kbase]) = pk;
                        }
                    }
                }
            }
            __syncthreads();

            #pragma unroll
            for (int s = 0; s < 10; ++s) {
                bf16x8 af = *reinterpret_cast<const bf16x8*>(&aT1[jt1 * 16 + c16][s * 32 + g4 * 8]);
                bf16x8 bf = *reinterpret_cast<const bf16x8*>(&aT2[jt2 * 16 + c16][s * 32 + g4 * 8]);
                gacc[i] = __builtin_amdgcn_mfma_f32_16x16x32_bf16(af, bf, gacc[i], 0, 0, 0);
            }
            __syncthreads();
        }
    }

    #pragma unroll
    for (int i = 0; i < 3; ++i) {
        const int j2 = jt2 * 16 + c16;
        #pragma unroll
        for (int r = 0; r < 4; ++r) {
            const int j1 = jt1 * 16 + g4 * 4 + r;
            if (j1 < 25 && j2 < 25)
                part[((size_t)(b * 3 + i) * SC_NSEG + seg) * 625 + j1 * 25 + j2] = gacc[i][r];
        }
    }
}

// ================= softmax (R19 text) =================
__global__ void softmax_kernel(const float* __restrict__ part,
                               const float* __restrict__ PA,
                               uint4* __restrict__ Gbg)
{
    int bi = blockIdx.x;
    int b = bi / 3, i = bi - b * 3;
    int j2 = threadIdx.x;
    if (j2 >= 32) return;
    float gval[25];
    if (j2 < 25) {
        float v[25];
        float m = -1e30f;
        #pragma unroll
        for (int j1 = 0; j1 < 25; ++j1) {
            float s = 0.0f;
            for (int seg = 0; seg < SC_NSEG; ++seg)
                s += part[((size_t)bi * SC_NSEG + seg) * 625 + j1 * 25 + j2];
            v[j1] = s * (1.0f / 9600.0f);
            m = fmaxf(m, v[j1]);
        }
        float sum = 0.0f;
        #pragma unroll
        for (int j1 = 0; j1 < 25; ++j1) { v[j1] = expf(v[j1] - m); sum += v[j1]; }
        float r = 1.0f / sum;
        #pragma unroll
        for (int j1 = 0; j1 < 25; ++j1)
            gval[j1] = v[j1] * r + PA[(i * 25 + j1) * 25 + j2] + (j1 == j2 ? 1.0f : 0.0f);
    }
    #pragma unroll
    for (int kg = 0; kg < 4; ++kg) {
        unsigned d[4];
        #pragma unroll
        for (int mm = 0; mm < 4; ++mm) {
            int ja = kg * 8 + 2 * mm, jb2 = ja + 1;
            float va = (j2 < 25 && ja < 25) ? gval[ja] : 0.0f;
            float vb = (j2 < 25 && jb2 < 25) ? gval[jb2] : 0.0f;
            d[mm] = pkbf(va, vb);
        }
        Gbg[((size_t)bi * 4 + kg) * 33 + j2] = make_uint4(d[0], d[1], d[2], d[3]);
    }
}

// ================= prep (R19 text: K-order [Wd0|Wdown|Wd1|Wd2]) =================
__global__ void prep_kernel(
    const float* __restrict__ Wd, const float* __restrict__ bd,
    const float* __restrict__ Wdown, const float* __restrict__ bdown,
    const float* __restrict__ g1, const float* __restrict__ b1,
    const float* __restrict__ m1, const float* __restrict__ v1,
    const float* __restrict__ g2, const float* __restrict__ b2,
    const float* __restrict__ m2, const float* __restrict__ v2,
    const float* __restrict__ Wa, const float* __restrict__ Wb,
    unsigned short* __restrict__ Wpb, float* __restrict__ cst,
    uint4* __restrict__ Wf)
{
    const int tid = threadIdx.x;
    for (int idx = tid; idx < COUT * 256; idx += 256) {
        int o = idx >> 8, k = idx & 255;
        int region = k >> 6;           // 0:Wd0 1:Wdown 2:Wd1 3:Wd2
        float val;
        if (region == 1) {
            float inv = g2[o] * rsqrtf(v2[o] + 1e-5f);
            val = Wdown[o * 64 + (k & 63)] * inv;
        } else {
            int i = (region == 0) ? 0 : region - 1;
            float inv = g1[o] * rsqrtf(v1[o] + 1e-5f);
            val = Wd[(i * COUT + o) * 64 + (k & 63)] * inv;
        }
        Wpb[idx] = f2bf(val);
    }
    for (int idx = tid; idx < 24 * 64; idx += 256) {
        const int fi = idx >> 6, lane = idx & 63;
        const int i = fi >> 3, pass = (fi >> 2) & 1, m = (fi >> 1) & 1, s = fi & 1;
        const int g4 = lane >> 4, c16 = lane & 15;
        const float* W = pass ? Wb : Wa;
        const float* wp = W + i * 2048 + (m * 16 + c16) * 64 + s * 32 + g4 * 8;
        Wf[idx] = make_uint4(pkbf(wp[0], wp[1]), pkbf(wp[2], wp[3]),
                             pkbf(wp[4], wp[5]), pkbf(wp[6], wp[7]));
    }
    if (tid < COUT) {
        int o = tid;
        float inv1 = g1[o] * rsqrtf(v1[o] + 1e-5f);
        float inv2 = g2[o] * rsqrtf(v2[o] + 1e-5f);
        cst[o] = (bd[o] + bd[COUT + o] + bd[2 * COUT + o]) * inv1
               + (b1[o] - m1[o] * inv1)
               + bdown[o] * inv2
               + (b2[o] - m2[o] * inv2);
    }
}

// ================= main fused kernel (R19 text — best measured) =================
#define M_NCH 75     // chunks of 4 t

__global__ __launch_bounds__(512, 8) void main_kernel(
    const uint4* __restrict__ xpk, const uint4* __restrict__ Gbg,
    const unsigned short* __restrict__ Wpb, const float* __restrict__ cst,
    float* __restrict__ out)
{
    __shared__ uint4 zxs[16][113];             // half-K B tile: [kgrp(8k)][pos]
    __shared__ uint4 gb[396];                  // [(i*4+kg)*33 + col]

    const int tid  = threadIdx.x;
    const int b    = blockIdx.y;
    const int t0   = blockIdx.x * 4;
    const int lane = tid & 63;
    const int w    = __builtin_amdgcn_readfirstlane(tid >> 6);  // wave 0..7
    const int g4   = lane >> 4;       // 0..3
    const int c16  = lane & 15;       // 0..15

    // ---- stage: x copy into zxs kgrps 8..15 — direct uint4 copy from xpk ----
    {
        const uint4* xpb = xpk + (size_t)b * 8 * 7500 + t0 * 25;
        for (int idx = tid; idx < 800; idx += 512) {
            int kgl = idx / 100, q = idx - kgl * 100;
            zxs[8 + kgl][q] = xpb[kgl * 7500 + q];
        }
    }
    if (tid < 396) gb[tid] = Gbg[(size_t)b * 396 + tid];

    f32x4 acc[7];
    #pragma unroll
    for (int n = 0; n < 7; ++n) acc[n] = (f32x4){0.f, 0.f, 0.f, 0.f};

    const int zt = w >> 1;            // wave's t row (0..3)
    const int mh = w & 1;             // wave's c-half

    __syncthreads();

    // z A-fragments (x_t rows) read from the zxs x-copy (registers carry them past overwrite)
    bf16x8 a_x[2];
    #pragma unroll
    for (int m = 0; m < 2; ++m) {
        const int cA = (mh * 2 + m) * 16 + c16;
        const unsigned short* src = (const unsigned short*)&zxs[8 + (cA >> 3)][zt * 25] + (cA & 7);
        bf16x8 t;
        #pragma unroll
        for (int e = 0; e < 8; ++e) {
            const int jp = g4 * 8 + e;
            t[e] = (jp < 25) ? (short)src[jp * 8] : (short)0;
        }
        a_x[m] = t;
    }

    // z-pass for subset i -> zxs kgrp base kb
    auto zpass = [&](int i, int kb) {
        #pragma unroll
        for (int n = 0; n < 2; ++n) {
            bf16x8 bfr = *reinterpret_cast<const bf16x8*>(&gb[(i * 4 + g4) * 33 + n * 16 + c16]);
            #pragma unroll
            for (int m = 0; m < 2; ++m) {
                f32x4 d = __builtin_amdgcn_mfma_f32_16x16x32_bf16(
                    a_x[m], bfr, (f32x4){0.f, 0.f, 0.f, 0.f}, 0, 0, 0);
                const int j = n * 16 + c16;
                if (j < 25) {
                    const int cb = (mh * 2 + m) * 16 + g4 * 4;   // lane's 4 c-rows start
                    const int kg = kb + (cb >> 3);
                    const int hf = (cb >> 2) & 1;
                    unsigned lo = pkbf(d[0], d[1]), hi = pkbf(d[2], d[3]);
                    *reinterpret_cast<uint2*>(
                        reinterpret_cast<char*>(&zxs[kg][zt * 25 + j]) + hf * 8) = make_uint2(lo, hi);
                }
            }
        }
    };

    zpass(0, 0);                       // z0 -> kgrps 0..7 (x already in 8..15)
    __syncthreads();

    // ---- GEMM h0 (k 0..127 = [Wd0 | Wdown]) ----
    {
        const unsigned short* wrow = Wpb + (w * 16 + c16) * 256 + g4 * 8;
        #pragma unroll
        for (int kk = 0; kk < 4; ++kk) {
            bf16x8 afr = *reinterpret_cast<const bf16x8*>(wrow + kk * 32);
            #pragma unroll
            for (int n = 0; n < 7; ++n) {
                bf16x8 bfr = *reinterpret_cast<const bf16x8*>(&zxs[kk * 4 + g4][n * 16 + c16]);
                acc[n] = __builtin_amdgcn_mfma_f32_16x16x32_bf16(afr, bfr, acc[n], 0, 0, 0);
            }
        }
    }
    __syncthreads();

    zpass(1, 0);                       // z1 -> kgrps 0..7
    zpass(2, 8);                       // z2 -> kgrps 8..15
    __syncthreads();

    // ---- GEMM h1 (k 128..255 = [Wd1 | Wd2]) ----
    {
        const unsigned short* wrow = Wpb + (w * 16 + c16) * 256 + 128 + g4 * 8;
        #pragma unroll
        for (int kk = 0; kk < 4; ++kk) {
            bf16x8 afr = *reinterpret_cast<const bf16x8*>(wrow + kk * 32);
            #pragma unroll
            for (int n = 0; n < 7; ++n) {
                bf16x8 bfr = *reinterpret_cast<const bf16x8*>(&zxs[kk * 4 + g4][n * 16 + c16]);
                acc[n] = __builtin_amdgcn_mfma_f32_16x16x32_bf16(afr, bfr, acc[n], 0, 0, 0);
            }
        }
    }

    // ---- epilogue: relu(acc + cst) -> out ----
    float* ob = out + (size_t)b * (COUT * T_DIM * J_DIM) + t0 * 25;
    #pragma unroll
    for (int r = 0; r < 4; ++r) {
        const int o = w * 16 + g4 * 4 + r;
        const float cv = cst[o];
        #pragma unroll
        for (int n = 0; n < 7; ++n) {
            const int pos = n * 16 + c16;
            if (pos < 100)
                ob[(size_t)o * 7500 + pos] = fmaxf(acc[n][r] + cv, 0.0f);
        }
    }
}

extern "C" void kernel_launch(void* const* d_in, const int* in_sizes, int n_in,
                              void* d_out, int out_size, void* d_ws, size_t ws_size,
                              hipStream_t stream)
{
    const float* x     = (const float*)d_in[0];
    const float* PA    = (const float*)d_in[1];
    const float* Wa    = (const float*)d_in[2];
    const float* ba    = (const float*)d_in[3];
    const float* Wb    = (const float*)d_in[4];
    const float* bb    = (const float*)d_in[5];
    const float* Wd    = (const float*)d_in[6];
    const float* bd    = (const float*)d_in[7];
    const float* Wdown = (const float*)d_in[8];
    const float* bdown = (const float*)d_in[9];
    const float* bn_g  = (const float*)d_in[10];
    const float* bn_b  = (const float*)d_in[11];
    const float* bn_m  = (const float*)d_in[12];
    const float* bn_v  = (const float*)d_in[13];
    const float* dn_g  = (const float*)d_in[14];
    const float* dn_b  = (const float*)d_in[15];
    const float* dn_m  = (const float*)d_in[16];
    const float* dn_v  = (const float*)d_in[17];

    float* ws   = (float*)d_ws;
    float* part = ws;                                      // 1,200,000 f32
    uint4* Gbg  = (uint4*)(ws + 1200000);                  // 64*396 uint4
    float* cst  = ws + 1301376;                            // 128 f32
    unsigned short* Wpb = (unsigned short*)(ws + 1301504); // 32,768 bf16 (16,384 f32)
    uint4* Wf   = (uint4*)(ws + 1317888);                  // 1536 uint4 (6,144 f32)
    uint4* xpk  = (uint4*)(ws + 1324032);                  // 64*8*7500 uint4 (15,360,000 f32)

    prep_kernel<<<1, 256, 0, stream>>>(Wd, bd, Wdown, bdown,
        bn_g, bn_b, bn_m, bn_v, dn_g, dn_b, dn_m, dn_v, Wa, Wb, Wpb, cst, Wf);
    scores_kernel<<<dim3(SC_NSEG, B_DIM), 256, 0, stream>>>(x, Wf, ba, bb, part, xpk);
    softmax_kernel<<<dim3(B_DIM * 3), 64, 0, stream>>>(part, PA, Gbg);
    main_kernel<<<dim3(M_NCH, B_DIM), 512, 0, stream>>>(xpk, Gbg, Wpb, cst, (float*)d_out);
}